// Round 10
// baseline (1775.658 us; speedup 1.0000x reference)
//
#include <hip/hip_runtime.h>
#include <hip/hip_bf16.h>

// LTC RNN: B=512, T=1024, D=64, H=256, O=64.  32 blocks x 16 batch rows, 8 waves.
// R9: back to 8 waves (2/SIMD — R8 proved 1 wave/SIMD exposes ~1700cyc of latency),
// plus: single barrier/step (dbuf h), x as global->register A-frags (no x in LDS),
// adjacent j-pair per lane (4x ds_write_b32), 3-op update, pk-cvt friendly packing.

typedef __attribute__((ext_vector_type(8))) short bf16x8;   // 8 bf16 (4 VGPRs)
typedef __attribute__((ext_vector_type(4))) float f32x4;

#define T_STEPS 1024
#define D_IN    64
#define H_DIM   256
#define O_DIM   64
#define ROWS    16
#define NTHREADS 512          // 8 waves, 2 per SIMD
#define HSTRIDE 512           // bytes per h-row: 256 bf16
#define BUFSZ   (ROWS * HSTRIDE)   // 8192 B per buffer

__device__ __forceinline__ short f2bf(float x) {
    __hip_bfloat16 b = __float2bfloat16(x);
    return *reinterpret_cast<short*>(&b);
}
__device__ __forceinline__ float sigm(float z) {
    float e = __builtin_amdgcn_exp2f(-1.4426950408889634f * z);   // exp(-z)
    return __builtin_amdgcn_rcpf(1.0f + e);
}
__device__ __forceinline__ bf16x8 pack8(f32x4 a, f32x4 b) {
    bf16x8 r;
    r[0]=f2bf(a[0]); r[1]=f2bf(a[1]); r[2]=f2bf(a[2]); r[3]=f2bf(a[3]);
    r[4]=f2bf(b[0]); r[5]=f2bf(b[1]); r[6]=f2bf(b[2]); r[7]=f2bf(b[3]);
    return r;
}

__global__ __launch_bounds__(NTHREADS, 2)
void ltc_kernel(const float* __restrict__ x_seq,  // [512,1024,64]
                const float* __restrict__ Wf,     // [256,320]
                const float* __restrict__ bf_,    // [256]
                const float* __restrict__ tau,    // [256]
                const float* __restrict__ Avec,   // [256]
                const float* __restrict__ Wo,     // [64,256]
                const float* __restrict__ bo,     // [64]
                float* __restrict__ out)          // [512,64] FLOAT32
{
    __shared__ alignas(64) char lds_raw[2 * BUFSZ];   // double-buffered h (bf16, swizzled)

    const int tid  = threadIdx.x;
    const int lane = tid & 63;
    const int w    = tid >> 6;        // wave 0..7
    const int lcol = lane & 15;
    const int lgrp = lane >> 4;       // 0..3
    const int brow0 = blockIdx.x * ROWS;
    const int j0 = w * 32 + 2 * lcol; // lane owns j0, j0+1 (C/D col = lcol, nt = 0,1)

    // ---------- Wf as B-fragments. Lane supplies B[k][n=lcol] = Wf[j0+nt][k].
    // h-part: bh[kt][nt], k = 64 + kt*32 + lgrp*8 + e (kt 0..7)
    // x-part: bx[kx][nt], k = kx*32 + lgrp*8 + e (kx 0..1)
    bf16x8 bh[8][2], bx[2][2];
    #pragma unroll
    for (int nt = 0; nt < 2; ++nt) {
        const float* wrow = Wf + (j0 + nt) * (D_IN + H_DIM);
        #pragma unroll
        for (int kt = 0; kt < 8; ++kt) {
            const int k0 = D_IN + kt * 32 + lgrp * 8;
            bh[kt][nt] = pack8(*(const f32x4*)(wrow + k0), *(const f32x4*)(wrow + k0 + 4));
        }
        #pragma unroll
        for (int kx = 0; kx < 2; ++kx) {
            const int k0 = kx * 32 + lgrp * 8;
            bx[kx][nt] = pack8(*(const f32x4*)(wrow + k0), *(const f32x4*)(wrow + k0 + 4));
        }
    }

    const float dt = 0.1f;
    float bias[2], ctau[2], cA[2];
    #pragma unroll
    for (int nt = 0; nt < 2; ++nt) {
        const int j = j0 + nt;
        bias[nt] = bf_[j];
        ctau[nt] = 1.0f - dt * __builtin_amdgcn_rcpf(__expf(tau[j])); // 1 - dt/exp(tau)
        cA[nt]   = dt * Avec[j];
    }

    // ---------- zero both h buffers (h0 = 0) ----------
    for (int i = tid; i < (2 * BUFSZ) / 4; i += NTHREADS)
        ((unsigned*)lds_raw)[i] = 0u;

    // ---------- x fragments: lane's A-row is lcol; k-slice lgrp*8..+8 (+32) ----------
    const float* xrow = x_seq + (size_t)(brow0 + lcol) * T_STEPS * D_IN + lgrp * 8;
    f32x4 nx0 = *(const f32x4*)(xrow);          // t=0, k = lgrp*8 .. +4
    f32x4 nx1 = *(const f32x4*)(xrow + 4);
    f32x4 nx2 = *(const f32x4*)(xrow + 32);     // k = 32 + lgrp*8 ..
    f32x4 nx3 = *(const f32x4*)(xrow + 36);

    __syncthreads();   // LDS zeroing complete

    bf16x8 xc0 = pack8(nx0, nx1);   // A-frag for kx=0, step 0
    bf16x8 xc1 = pack8(nx2, nx3);   // A-frag for kx=1, step 0

    // ---------- hoisted LDS addresses ----------
    const int aswz  = (lcol & 7) << 4;
    const int rbase = lcol * HSTRIDE;
    int roff[8];
    #pragma unroll
    for (int kt = 0; kt < 8; ++kt)
        roff[kt] = rbase + ((kt * 64 + lgrp * 16) ^ aswz);
    int woff[4];
    #pragma unroll
    for (int r = 0; r < 4; ++r) {
        const int m = lgrp * 4 + r;
        // byte = 2*j0 (4B-aligned since j0 even), XOR row swizzle
        woff[r] = m * HSTRIDE + ((2 * j0) ^ ((m & 7) << 4));
    }

    // fp32 master state: h0[r] (col j0), h1[r] (col j0+1) at row m = lgrp*4+r
    float h0[4] = {0.f, 0.f, 0.f, 0.f};
    float h1[4] = {0.f, 0.f, 0.f, 0.f};

    for (int t = 0; t < T_STEPS; ++t) {
        const char* rbuf = lds_raw + (t & 1) * BUFSZ;
        char*       wbuf = lds_raw + ((t & 1) ^ 1) * BUFSZ;

        // h A-fragments for step t
        bf16x8 ah[8];
        #pragma unroll
        for (int kt = 0; kt < 8; ++kt)
            ah[kt] = *(const bf16x8*)(rbuf + roff[kt]);

        // prefetch x_{t+1} fragments (consumed ~full-step later at cvt)
        const int tn = (t + 1 < T_STEPS) ? (t + 1) : t;
        const float* xp = xrow + (size_t)tn * D_IN;
        nx0 = *(const f32x4*)(xp);
        nx1 = *(const f32x4*)(xp + 4);
        nx2 = *(const f32x4*)(xp + 32);
        nx3 = *(const f32x4*)(xp + 36);

        // z = bias + x@Wx^T + h@Wh^T   (x-MFMAs first: register-only, no lgkm dep)
        f32x4 a0 = { bias[0], bias[0], bias[0], bias[0] };
        f32x4 a1 = { bias[1], bias[1], bias[1], bias[1] };
        a0 = __builtin_amdgcn_mfma_f32_16x16x32_bf16(xc0, bx[0][0], a0, 0, 0, 0);
        a1 = __builtin_amdgcn_mfma_f32_16x16x32_bf16(xc0, bx[0][1], a1, 0, 0, 0);
        a0 = __builtin_amdgcn_mfma_f32_16x16x32_bf16(xc1, bx[1][0], a0, 0, 0, 0);
        a1 = __builtin_amdgcn_mfma_f32_16x16x32_bf16(xc1, bx[1][1], a1, 0, 0, 0);
        #pragma unroll
        for (int kt = 0; kt < 8; ++kt) {
            a0 = __builtin_amdgcn_mfma_f32_16x16x32_bf16(ah[kt], bh[kt][0], a0, 0, 0, 0);
            a1 = __builtin_amdgcn_mfma_f32_16x16x32_bf16(ah[kt], bh[kt][1], a1, 0, 0, 0);
        }

        // epilogue: f = sigmoid(z); h = h*ctau + f*(cA - dt*h); pack (j0, j0+1) pairs
        unsigned hw[4];
        #pragma unroll
        for (int r = 0; r < 4; ++r) {
            float f0 = sigm(a0[r]);
            float u0 = cA[0] - dt * h0[r];
            h0[r] = h0[r] * ctau[0] + f0 * u0;
            float f1 = sigm(a1[r]);
            float u1 = cA[1] - dt * h1[r];
            h1[r] = h1[r] * ctau[1] + f1 * u1;
            hw[r] = ((unsigned)(unsigned short)f2bf(h1[r]) << 16)
                  |  (unsigned)(unsigned short)f2bf(h0[r]);
        }

        // convert next-step x frags (forces vmcnt wait here, ~full step after issue)
        xc0 = pack8(nx0, nx1);
        xc1 = pack8(nx2, nx3);

        // write h_{t+1} into the other buffer (no pre-barrier needed: disjoint bufs)
        #pragma unroll
        for (int r = 0; r < 4; ++r)
            *(unsigned*)(wbuf + woff[r]) = hw[r];

        __syncthreads();   // single barrier: buf[(t+1)&1] fully staged
    }

    // ---------- out = h_T @ Wo^T + bo ; h_T (bf16) in buf0 (1024 even) ----------
    if (w < 4) {
        const char* fbuf = lds_raw;
        bf16x8 ha[8];
        #pragma unroll
        for (int kt = 0; kt < 8; ++kt)
            ha[kt] = *(const bf16x8*)(fbuf + roff[kt]);
        const int o = w * 16 + lcol;              // lane supplies Wo[o][k]; C/D col -> o
        const float* worow = Wo + o * H_DIM;
        const float bov = bo[o];
        f32x4 acc = { bov, bov, bov, bov };
        #pragma unroll
        for (int kt = 0; kt < 8; ++kt) {
            const int k0 = kt * 32 + lgrp * 8;
            acc = __builtin_amdgcn_mfma_f32_16x16x32_bf16(
                ha[kt], pack8(*(const f32x4*)(worow + k0), *(const f32x4*)(worow + k0 + 4)),
                acc, 0, 0, 0);
        }
        #pragma unroll
        for (int r = 0; r < 4; ++r) {
            const int m = lgrp * 4 + r;           // C/D row = (lane>>4)*4 + reg
            out[(size_t)(brow0 + m) * O_DIM + o] = acc[r];
        }
    }
}

extern "C" void kernel_launch(void* const* d_in, const int* in_sizes, int n_in,
                              void* d_out, int out_size, void* d_ws, size_t ws_size,
                              hipStream_t stream) {
    const float* x_seq = (const float*)d_in[0];
    const float* Wf    = (const float*)d_in[1];
    const float* bf_   = (const float*)d_in[2];
    const float* tau   = (const float*)d_in[3];
    const float* Avec  = (const float*)d_in[4];
    const float* Wo    = (const float*)d_in[5];
    const float* bo    = (const float*)d_in[6];
    float* out = (float*)d_out;   // reference output dtype is float32

    ltc_kernel<<<512 / ROWS, NTHREADS, 0, stream>>>(x_seq, Wf, bf_, tau, Avec, Wo, bo, out);
}